// Round 3
// baseline (31095.163 us; speedup 1.0000x reference)
//
#include <hip/hip_runtime.h>
#include <hip/hip_bf16.h>

typedef __bf16 bf16;
typedef __bf16 bf16x8 __attribute__((ext_vector_type(8)));
typedef float  f32x4  __attribute__((ext_vector_type(4)));

#define NT   600
#define NB   128
#define NS   512
#define NU   96
#define NK   10
#define NC   80
#define NOUT 121

// packed-weight element offsets in ws (bf16 elements), layout [slab][kb][lane][8]
#define W1X_J 0
#define W1W_J 16384
#define W1H_J 65536
#define W1X_K 327680
#define W1W_K 344064
#define W1H_K 393216
#define W2X_J 655360
#define W2W_J 671744
#define W2A_J 720896
#define W2H_J 983040
#define W2X_K 1245184
#define W2W_K 1261568
#define W2A_K 1310720
#define W2H_K 1572864
#define WWIN  1835008
#define WLIN  1851392
#define WTOT  1916928                 // bf16 elements -> 3,833,856 bytes

#define BIAS_BYTE_OFF 3833856         // 2048 floats: [b1j|b1k|b2j|b2k]
#define H_BYTE_OFF    3842048         // h1[2][128][512], h2..., h3... bf16
#define HBUF 65536                    // elements per parity buffer
#define KAP_BYTE_OFF  4628480         // float kap[2][128][10]
#define WBUF_BYTE_OFF 4638720         // bf16 wbuf[128][80]
#define FLAG_BYTE_OFF 4659200         // int isF32

// dual-dtype input load: isF32 is wave-uniform; if/else so the untaken
// (possibly OOB) load is never issued.
__device__ __forceinline__ float ldIn(const void* q, long i, int isF32) {
  if (isF32) return ((const float*)q)[i];
  return (float)((const bf16*)q)[i];
}

struct KParams {
  const void* x;       // [128][600][3]
  const void* c_vec;   // [128][96][80]
  const void* b_win;   // [30]
  const void* b_lin;   // [121]
  const bf16* W;       // packed weights base
  const float* bias;   // [4*512]
  bf16* h1; bf16* h2; bf16* h3;  // [2][128][512] each
  float* kap;          // [2][128][10]
  bf16* wbuf;          // [128][80]
  void* out;           // [128*600][121]
  const int* flag;
};

// ---------------- sniff: decide f32 vs bf16 input encoding ----------------
// Even-index uint16s of W_jh1: bf16 data -> N(0,0.05) samples, exponent field
// ~[110,125], anomaly rate ~0. f32 data -> mantissa halves, uniform bits,
// ~38% anomalies. 8192 samples, threshold 512: fully decisive.
__global__ void sniff_kernel(const unsigned short* w, int* flag) {
  __shared__ int cnt;
  if (threadIdx.x == 0) cnt = 0;
  __syncthreads();
  int c = 0;
  for (int i = threadIdx.x; i < 8192; i += 256) {
    unsigned e = (w[2 * i] >> 7) & 0xFF;
    if (e == 0xFF || e < 96) c++;
  }
  atomicAdd(&cnt, c);
  __syncthreads();
  if (threadIdx.x == 0) *flag = (cnt > 512) ? 1 : 0;
}

// ---------------- prep: repack weights + zero state ----------------
__global__ void prep_kernel(const void* Wjx1, const void* Wjh1, const void* Wkx1, const void* Wkh1,
                            const void* Wjx2, const void* Wjh2, const void* Wkx2, const void* Wkh2,
                            const void* Wwin, const void* Wlin,
                            const void* bjx1, const void* bjh1, const void* bkx1, const void* bkh1,
                            const void* bjx2, const void* bjh2, const void* bkx2, const void* bkh2,
                            bf16* W, float* bias,
                            bf16* h1, bf16* h2, bf16* h3, float* kap, bf16* wbuf,
                            const int* flag) {
  const int isF32 = *flag;
  const int r = blockIdx.y;
  const int e = blockIdx.x * 256 + threadIdx.x;
  if (r == 16) {                       // combined biases (f32)
    if (e < 512) {
      bias[e]        = ldIn(bjx1, e, isF32) + ldIn(bjh1, e, isF32);
      bias[512 + e]  = ldIn(bkx1, e, isF32) + ldIn(bkh1, e, isF32);
      bias[1024 + e] = ldIn(bjx2, e, isF32) + ldIn(bjh2, e, isF32);
      bias[1536 + e] = ldIn(bkx2, e, isF32) + ldIn(bkh2, e, isF32);
    }
    return;
  }
  if (r == 17) {                       // zero parity-1 state + kap + wbuf
    if (e < HBUF) {
      h1[HBUF + e] = (bf16)0.f;
      h2[HBUF + e] = (bf16)0.f;
      h3[HBUF + e] = (bf16)0.f;
    }
    if (e < 2 * 128 * NK) kap[e] = 0.f;
    if (e < 128 * NC) wbuf[e] = (bf16)0.f;
    return;
  }
  const int   row0s[16]  = {0,3,0, 0,3,0, 0,515,3,0, 0,515,3,0, 0,0};
  const int   klens[16]  = {3,80,512, 3,80,512, 3,80,512,512, 3,80,512,512, 512,512};
  const int   kpads[16]  = {32,96,512, 32,96,512, 32,96,512,512, 32,96,512,512, 512,512};
  const int   cpads[16]  = {512,512,512, 512,512,512, 512,512,512,512, 512,512,512,512, 32,128};
  const int   nsrcs[16]  = {512,512,512, 512,512,512, 512,512,512,512, 512,512,512,512, 30,121};
  const long  offs[16]   = {W1X_J,W1W_J,W1H_J, W1X_K,W1W_K,W1H_K,
                            W2X_J,W2W_J,W2A_J,W2H_J, W2X_K,W2W_K,W2A_K,W2H_K, WWIN,WLIN};
  const void* srcs[16]   = {Wjx1,Wjx1,Wjh1, Wkx1,Wkx1,Wkh1,
                            Wjx2,Wjx2,Wjx2,Wjh2, Wkx2,Wkx2,Wkx2,Wkh2, Wwin,Wlin};
  const int Kpad = kpads[r], cp = cpads[r];
  const long tot = (long)Kpad * cp;
  if (e >= tot) return;
  const int j    = e & 7;
  const int lane = (e >> 3) & 63;
  const int rest = e >> 9;
  const int kbs  = Kpad >> 5;
  const int kb   = rest % kbs;
  const int slab = rest / kbs;
  const int col  = slab * 16 + (lane & 15);
  const int k    = kb * 32 + ((lane >> 4) << 3) + j;
  const int Klen = klens[r], row0 = row0s[r], N = nsrcs[r];
  bf16 v = (bf16)0.f;
  if (k < Klen && col < N) v = (bf16)ldIn(srcs[r], (long)(row0 + k) * N + col, isF32);
  W[offs[r] + e] = v;
}

// ---------------- shared MFMA helper ----------------
__device__ __forceinline__ void accum_term(f32x4& acc, int& cnt, int kh,
    const bf16* Arow, int astride, const bf16* B, int kbs,
    int lr, int ko, int lane) {
  for (int kb = 0; kb < kbs; ++kb) {
    if (((cnt++) & 1) != kh) continue;
    bf16x8 a = *(const bf16x8*)(Arow + (size_t)lr * astride + kb * 32 + ko);
    bf16x8 b = *(const bf16x8*)(B + ((size_t)kb * 64 + lane) * 8);
    acc = __builtin_amdgcn_mfma_f32_16x16x32_bf16(a, b, acc, 0, 0, 0);
  }
}

// ================= Stage P: attention(t) + ff2(t) + out-head(t-1) =================
__global__ __launch_bounds__(256) void stageP_kernel(KParams p, int t) {
  const int isF32 = *p.flag;
  const int tid  = threadIdx.x;
  const int wid  = tid >> 6;
  const int lane = tid & 63;
  const int wg   = blockIdx.x;       // 256 WGs
  const int m    = wg >> 5;
  const int slab = wg & 31;
  const int m16  = m << 4;
  const int lr   = lane & 15;
  const int ko   = (lane >> 4) << 3;
  const int g    = wid >> 1;
  const int kh   = wid & 1;
  const int par_t = t & 1;
  const int par_p = (t + 1) & 1;

  __shared__ alignas(16) bf16 xtL[16][32];
  __shared__ alignas(16) bf16 wL[16][96];
  __shared__ float kgL[16][32];
  __shared__ float kapL[16][NK];
  __shared__ float alphaL[16][NK];
  __shared__ float betaL[16][NK];
  __shared__ float wloL[16][16];
  __shared__ float whiL[16][16];
  __shared__ int   winL[16][2];
  __shared__ float phiL[16][NU];
  __shared__ f32x4 accA[4][64];
  __shared__ f32x4 accB[4][64];

  // zero LDS A-tiles (padding must not be garbage)
  for (int i = tid; i < 16 * 32; i += 256) (&xtL[0][0])[i] = (bf16)0.f;
  for (int i = tid; i < 16 * 96; i += 256) (&wL[0][0])[i] = (bf16)0.f;
  __syncthreads();

  if (tid < 48) {
    int row = tid / 3, d = tid - row * 3;
    xtL[row][d] = (bf16)ldIn(p.x, ((long)(m16 + row) * NT + t) * 3 + d, isF32);
  }
  const bf16* h1t = p.h1 + (size_t)par_t * HBUF;
  {  // kg = h1(t) @ W_win via MFMA
    int n2 = wid & 1, kh2 = wid >> 1;
    f32x4 acc = {0.f, 0.f, 0.f, 0.f};
    const bf16* A = h1t + (size_t)m16 * NS;
    const bf16* B = p.W + WWIN + (size_t)n2 * (16 * NS);
    for (int kb = 0; kb < 16; ++kb) {
      if ((kb & 1) != kh2) continue;
      bf16x8 a = *(const bf16x8*)(A + (size_t)lr * NS + kb * 32 + ko);
      bf16x8 b = *(const bf16x8*)(B + ((size_t)kb * 64 + lane) * 8);
      acc = __builtin_amdgcn_mfma_f32_16x16x32_bf16(a, b, acc, 0, 0, 0);
    }
    accA[wid][lane] = acc;
  }
  __syncthreads();
  if (tid < 128) {  // kg epilogue
    int ls = tid & 63, n2s = tid >> 6;
    int o = n2s * 16 + (ls & 15);
    if (o < 30) {
      int rowb = (ls >> 4) << 2;
      for (int r = 0; r < 4; ++r)
        kgL[rowb + r][o] = accA[n2s][ls][r] + accA[n2s + 2][ls][r] + ldIn(p.b_win, o, isF32);
    }
  }
  __syncthreads();
  {  // attention scalars
    int arow = tid >> 4, aj = tid & 15;
    if (aj < NK) {
      float ah = kgL[arow][aj];
      float be = expf(kgL[arow][NK + aj]);
      float dk = expf(kgL[arow][2 * NK + aj]);
      float al = expf(ah);
      float kap = p.kap[(size_t)par_p * 1280 + (m16 + arow) * NK + aj] + dk;
      if (slab == 0) p.kap[(size_t)par_t * 1280 + (m16 + arow) * NK + aj] = kap;
      kapL[arow][aj] = kap;
      alphaL[arow][aj] = al;
      betaL[arow][aj] = be;
      float arg = (ah + 18.42f) / be;
      float lo, hi;
      if (arg > 0.f) { float R = sqrtf(arg); lo = kap - R; hi = kap + R; }
      else           { lo = 1e30f; hi = -1e30f; }
      wloL[arow][aj] = lo; whiL[arow][aj] = hi;
    } else { wloL[arow][aj] = 1e30f; whiL[arow][aj] = -1e30f; }
    __syncthreads();
    if (aj == 0) {
      float lo = 1e30f, hi = -1e30f;
      for (int k2 = 0; k2 < NK; ++k2) { lo = fminf(lo, wloL[arow][k2]); hi = fmaxf(hi, whiL[arow][k2]); }
      int ulo = (lo <= 0.f) ? 0 : ((lo > 95.f) ? 96 : (int)floorf(lo));
      int uhi = (hi >= 95.f) ? 95 : ((hi < 0.f) ? -1 : (int)ceilf(hi));
      winL[arow][0] = ulo; winL[arow][1] = uhi;
    }
    __syncthreads();
    const int ulo = winL[arow][0], uhi = winL[arow][1];
    for (int u = ulo + aj; u <= uhi; u += 16) {
      float s = 0.f, uf = (float)u;
      for (int k2 = 0; k2 < NK; ++k2) {
        float d = kapL[arow][k2] - uf;
        s += alphaL[arow][k2] * __expf(-betaL[arow][k2] * d * d);
      }
      phiL[arow][u] = s;
    }
    __syncthreads();
    {  // w = phi @ c_vec[b]
      const long cv0 = (long)(m16 + arow) * NU * NC;
      for (int c = aj; c < NC; c += 16) {
        float acc = 0.f;
        for (int u = ulo; u <= uhi; ++u)
          acc += phiL[arow][u] * ldIn(p.c_vec, cv0 + (long)u * NC + c, isF32);
        bf16 wv = (bf16)acc;
        wL[arow][c] = wv;
        if (slab == 0) p.wbuf[(size_t)(m16 + arow) * NC + c] = wv;
      }
    }
  }
  __syncthreads();
  {  // ff2 MFMAs: in2 = [xt, h1(t), w], recur h2(t-1)
    f32x4 acc = {0.f, 0.f, 0.f, 0.f};
    int cnt = 0;
    const size_t oX = g ? W2X_K : W2X_J, oA = g ? W2A_K : W2A_J;
    const size_t oW = g ? W2W_K : W2W_J, oH = g ? W2H_K : W2H_J;
    accum_term(acc, cnt, kh, &xtL[0][0], 32, p.W + oX + (size_t)slab * NS,        1,  lr, ko, lane);
    accum_term(acc, cnt, kh, h1t + (size_t)m16 * NS, NS, p.W + oA + (size_t)slab * (16 * NS), 16, lr, ko, lane);
    accum_term(acc, cnt, kh, &wL[0][0], 96, p.W + oW + (size_t)slab * (3 * NS),   3,  lr, ko, lane);
    accum_term(acc, cnt, kh, p.h2 + (size_t)par_p * HBUF + (size_t)m16 * NS, NS,
               p.W + oH + (size_t)slab * (16 * NS), 16, lr, ko, lane);
    accA[wid][lane] = acc;
  }
  if (slab < 8 && t >= 1) {  // out-head MFMAs for rows (t-1)
    f32x4 acc = {0.f, 0.f, 0.f, 0.f};
    const bf16* A = p.h3 + (size_t)par_p * HBUF + (size_t)m16 * NS;
    const bf16* B = p.W + WLIN + (size_t)slab * (16 * NS);
    for (int kb = 0; kb < 16; ++kb) {
      if ((kb & 3) != wid) continue;
      bf16x8 a = *(const bf16x8*)(A + (size_t)lr * NS + kb * 32 + ko);
      bf16x8 b = *(const bf16x8*)(B + ((size_t)kb * 64 + lane) * 8);
      acc = __builtin_amdgcn_mfma_f32_16x16x32_bf16(a, b, acc, 0, 0, 0);
    }
    accB[wid][lane] = acc;
  }
  __syncthreads();
  {  // ff2 epilogue -> h2(t)
    int ls = tid & 63, r = tid >> 6;
    int s = (slab << 4) + (ls & 15);
    int b = m16 + ((ls >> 4) << 2) + r;
    float jp = accA[0][ls][r] + accA[1][ls][r] + p.bias[1024 + s];
    float kp = accA[2][ls][r] + accA[3][ls][r] + p.bias[1536 + s];
    float ho = (float)p.h2[(size_t)par_p * HBUF + (size_t)b * NS + s];
    float jj = 1.f / (1.f + __expf(-jp));
    float kk = 1.f / (1.f + __expf(-kp));
    p.h2[(size_t)par_t * HBUF + (size_t)b * NS + s] = (bf16)(jj * (1.f - ho) + (1.f - kk) * ho);
  }
  if (slab < 8 && t >= 1 && tid < 64) {  // out-head epilogue
    int o = (slab << 4) + (tid & 15);
    if (o < NOUT) {
      float bl = ldIn(p.b_lin, o, isF32);
      int rb = (tid >> 4) << 2;
      for (int r = 0; r < 4; ++r) {
        float v = accB[0][tid][r] + accB[1][tid][r] + accB[2][tid][r] + accB[3][tid][r] + bl;
        long oi = ((long)(m16 + rb + r) * NT + (t - 1)) * NOUT + o;
        if (isF32) ((float*)p.out)[oi] = v; else ((bf16*)p.out)[oi] = (bf16)v;
      }
    }
  }
}

// ================= Stage Q: ff3(t) + ff1(t+1) =================
__global__ __launch_bounds__(256) void stageQ_kernel(KParams p, int t) {
  const int isF32 = *p.flag;
  const int tid  = threadIdx.x;
  const int wid  = tid >> 6;
  const int lane = tid & 63;
  const int wg   = blockIdx.x;
  const int m    = wg >> 5;
  const int slab = wg & 31;
  const int m16  = m << 4;
  const int lr   = lane & 15;
  const int ko   = (lane >> 4) << 3;
  const int g    = wid >> 1;
  const int kh   = wid & 1;
  const int par_t = t & 1;        // (-1)&1 == 1
  const int par_p = (t + 1) & 1;

  __shared__ alignas(16) bf16 xtL[16][32];
  __shared__ alignas(16) bf16 xt2L[16][32];
  __shared__ alignas(16) bf16 wL[16][96];
  __shared__ f32x4 accA[4][64];
  __shared__ f32x4 accB[4][64];

  for (int i = tid; i < 16 * 32; i += 256) { (&xtL[0][0])[i] = (bf16)0.f; (&xt2L[0][0])[i] = (bf16)0.f; }
  for (int i = tid; i < 16 * 96; i += 256) (&wL[0][0])[i] = (bf16)0.f;
  __syncthreads();

  if (t >= 0 && tid < 48) {
    int row = tid / 3, d = tid - row * 3;
    xtL[row][d] = (bf16)ldIn(p.x, ((long)(m16 + row) * NT + t) * 3 + d, isF32);
  }
  if (t < NT - 1 && tid < 48) {
    int row = tid / 3, d = tid - row * 3;
    xt2L[row][d] = (bf16)ldIn(p.x, ((long)(m16 + row) * NT + (t + 1)) * 3 + d, isF32);
  }
  for (int i = tid; i < 16 * NC; i += 256) {
    int row = i / NC, c = i - row * NC;
    wL[row][c] = p.wbuf[(size_t)(m16 + row) * NC + c];
  }
  __syncthreads();

  const bf16* h1t = p.h1 + (size_t)par_t * HBUF;
  f32x4 acc3 = {0.f, 0.f, 0.f, 0.f};
  f32x4 acc1 = {0.f, 0.f, 0.f, 0.f};
  if (t >= 0) {  // ff3: in3 = [xt, h2(t), w], recur h3(t-1)
    int cnt = 0;
    const size_t oX = g ? W2X_K : W2X_J, oA = g ? W2A_K : W2A_J;
    const size_t oW = g ? W2W_K : W2W_J, oH = g ? W2H_K : W2H_J;
    accum_term(acc3, cnt, kh, &xtL[0][0], 32, p.W + oX + (size_t)slab * NS,        1,  lr, ko, lane);
    accum_term(acc3, cnt, kh, p.h2 + (size_t)par_t * HBUF + (size_t)m16 * NS, NS,
               p.W + oA + (size_t)slab * (16 * NS), 16, lr, ko, lane);
    accum_term(acc3, cnt, kh, &wL[0][0], 96, p.W + oW + (size_t)slab * (3 * NS),   3,  lr, ko, lane);
    accum_term(acc3, cnt, kh, p.h3 + (size_t)par_p * HBUF + (size_t)m16 * NS, NS,
               p.W + oH + (size_t)slab * (16 * NS), 16, lr, ko, lane);
  }
  if (t < NT - 1) {  // ff1(t+1): in1 = [xt(t+1), w(t)], recur h1(t)
    int cnt = 0;
    const size_t oX = g ? W1X_K : W1X_J, oW = g ? W1W_K : W1W_J, oH = g ? W1H_K : W1H_J;
    accum_term(acc1, cnt, kh, &xt2L[0][0], 32, p.W + oX + (size_t)slab * NS,       1,  lr, ko, lane);
    accum_term(acc1, cnt, kh, &wL[0][0], 96, p.W + oW + (size_t)slab * (3 * NS),   3,  lr, ko, lane);
    accum_term(acc1, cnt, kh, h1t + (size_t)m16 * NS, NS, p.W + oH + (size_t)slab * (16 * NS), 16, lr, ko, lane);
  }
  accA[wid][lane] = acc3;
  accB[wid][lane] = acc1;
  __syncthreads();
  {
    int ls = tid & 63, r = tid >> 6;
    int s = (slab << 4) + (ls & 15);
    int b = m16 + ((ls >> 4) << 2) + r;
    if (t >= 0) {  // h3(t)
      float jp = accA[0][ls][r] + accA[1][ls][r] + p.bias[1024 + s];
      float kp = accA[2][ls][r] + accA[3][ls][r] + p.bias[1536 + s];
      float ho = (float)p.h3[(size_t)par_p * HBUF + (size_t)b * NS + s];
      float jj = 1.f / (1.f + __expf(-jp));
      float kk = 1.f / (1.f + __expf(-kp));
      p.h3[(size_t)par_t * HBUF + (size_t)b * NS + s] = (bf16)(jj * (1.f - ho) + (1.f - kk) * ho);
    }
    if (t < NT - 1) {  // h1(t+1)
      float jp = accB[0][ls][r] + accB[1][ls][r] + p.bias[0 + s];
      float kp = accB[2][ls][r] + accB[3][ls][r] + p.bias[512 + s];
      float ho = (float)p.h1[(size_t)par_t * HBUF + (size_t)b * NS + s];
      float jj = 1.f / (1.f + __expf(-jp));
      float kk = 1.f / (1.f + __expf(-kp));
      p.h1[(size_t)par_p * HBUF + (size_t)b * NS + s] = (bf16)(jj * (1.f - ho) + (1.f - kk) * ho);
    }
  }
}

// ================= final out-head: row t = 599 (h3(599) in parity 1) =================
__global__ __launch_bounds__(256) void final_head_kernel(KParams p) {
  const int isF32 = *p.flag;
  const int tid  = threadIdx.x;
  const int wid  = tid >> 6;
  const int lane = tid & 63;
  const int wg   = blockIdx.x;       // 64 WGs
  const int m    = wg >> 3;
  const int slab = wg & 7;
  const int m16  = m << 4;
  const int lr   = lane & 15;
  const int ko   = (lane >> 4) << 3;
  __shared__ f32x4 accB[4][64];

  f32x4 acc = {0.f, 0.f, 0.f, 0.f};
  const bf16* A = p.h3 + (size_t)HBUF + (size_t)m16 * NS;
  const bf16* B = p.W + WLIN + (size_t)slab * (16 * NS);
  for (int kb = 0; kb < 16; ++kb) {
    if ((kb & 3) != wid) continue;
    bf16x8 a = *(const bf16x8*)(A + (size_t)lr * NS + kb * 32 + ko);
    bf16x8 b = *(const bf16x8*)(B + ((size_t)kb * 64 + lane) * 8);
    acc = __builtin_amdgcn_mfma_f32_16x16x32_bf16(a, b, acc, 0, 0, 0);
  }
  accB[wid][lane] = acc;
  __syncthreads();
  if (tid < 64) {
    int o = (slab << 4) + (tid & 15);
    if (o < NOUT) {
      float bl = ldIn(p.b_lin, o, isF32);
      int rb = (tid >> 4) << 2;
      for (int r = 0; r < 4; ++r) {
        float v = accB[0][tid][r] + accB[1][tid][r] + accB[2][tid][r] + accB[3][tid][r] + bl;
        long oi = ((long)(m16 + rb + r) * NT + (NT - 1)) * NOUT + o;
        if (isF32) ((float*)p.out)[oi] = v; else ((bf16*)p.out)[oi] = (bf16)v;
      }
    }
  }
}

extern "C" void kernel_launch(void* const* d_in, const int* in_sizes, int n_in,
                              void* d_out, int out_size, void* d_ws, size_t ws_size,
                              hipStream_t stream) {
  (void)in_sizes; (void)n_in; (void)out_size; (void)ws_size;

  bf16*  wsW  = (bf16*)d_ws;
  float* bias = (float*)((char*)d_ws + BIAS_BYTE_OFF);
  bf16*  h1   = (bf16*)((char*)d_ws + H_BYTE_OFF);
  bf16*  h2   = h1 + 2 * HBUF;
  bf16*  h3   = h2 + 2 * HBUF;
  float* kap  = (float*)((char*)d_ws + KAP_BYTE_OFF);
  bf16*  wbuf = (bf16*)((char*)d_ws + WBUF_BYTE_OFF);
  int*   flag = (int*)((char*)d_ws + FLAG_BYTE_OFF);

  sniff_kernel<<<1, 256, 0, stream>>>((const unsigned short*)d_in[4], flag);

  prep_kernel<<<dim3(1024, 18), 256, 0, stream>>>(
      d_in[2], d_in[4], d_in[6], d_in[8], d_in[10], d_in[12], d_in[14], d_in[16],
      d_in[18], d_in[20],
      d_in[3], d_in[5], d_in[7], d_in[9], d_in[11], d_in[13], d_in[15], d_in[17],
      wsW, bias, h1, h2, h3, kap, wbuf, flag);

  KParams kp;
  kp.x = d_in[0]; kp.c_vec = d_in[1]; kp.b_win = d_in[19]; kp.b_lin = d_in[21];
  kp.W = wsW; kp.bias = bias;
  kp.h1 = h1; kp.h2 = h2; kp.h3 = h3;
  kp.kap = kap; kp.wbuf = wbuf;
  kp.out = d_out;
  kp.flag = flag;

  stageQ_kernel<<<256, 256, 0, stream>>>(kp, -1);
  for (int t = 0; t < NT; ++t) {
    stageP_kernel<<<256, 256, 0, stream>>>(kp, t);
    stageQ_kernel<<<256, 256, 0, stream>>>(kp, t);
  }
  final_head_kernel<<<64, 256, 0, stream>>>(kp);
}